// Round 2
// baseline (684.015 us; speedup 1.0000x reference)
//
#include <hip/hip_runtime.h>
#include <math.h>

#define B_ 4
#define T_ 64
#define N_ 2048
#define C_ 32
#define H_ 64
#define M_ (B_*N_)      // 8192
#define SPB 32          // samples per GRU block
#define SLOPE 0.2f

// Dynamic LDS layout (floats):
//   whh : [64][192]  (k-major, transposed W_hh)        12288
//   wih : [32][192]  (k-major, transposed W_ih)         6144
//   hbuf: [64][SPB]  (k-major hidden state)             2048
//   xbuf: [32][SPB]  (c-major current x tile)           1024
#define LDS_FLOATS (64*192 + 32*192 + 64*SPB + 32*SPB)
#define LDS_BYTES (LDS_FLOATS*4)

__device__ __forceinline__ float lrelu(float v) { return v >= 0.f ? v : SLOPE * v; }

extern __shared__ float lds[];

__global__ __launch_bounds__(256) void gru_kernel(
    const float* __restrict__ x,      // [B,T,N,C]
    const float* __restrict__ w_ih,   // [192][32]
    const float* __restrict__ w_hh,   // [192][64]
    const float* __restrict__ b_ih,   // [192]
    const float* __restrict__ b_hh,   // [192]
    float* __restrict__ h_last)       // [M][H]  (lives in d_out scratch)
{
    float* whh  = lds;                    // [64][192]
    float* wih  = lds + 64*192;           // [32][192]
    float* hbuf = lds + 96*192;           // [64][SPB]
    float* xbuf = hbuf + 64*SPB;          // [32][SPB]

    const int tid = threadIdx.x;
    const int j   = tid & 63;             // hidden index (lane)
    const int sg  = tid >> 6;             // sample group 0..3
    const int s0  = sg * 8;

    const int m0 = blockIdx.x * SPB;      // first sample of block
    const int b  = m0 >> 11;              // /2048
    const int n0 = m0 & 2047;

    // Stage W transposed into LDS (once)
    for (int idx = tid; idx < 192*64; idx += 256) {
        int jp = idx >> 6, k = idx & 63;
        whh[k*192 + jp] = w_hh[idx];
    }
    for (int idx = tid; idx < 192*32; idx += 256) {
        int jp = idx >> 5, k = idx & 31;
        wih[k*192 + jp] = w_ih[idx];
    }
    for (int idx = tid; idx < 64*SPB; idx += 256) hbuf[idx] = 0.f;

    const float br  = b_ih[j]       + b_hh[j];
    const float bz  = b_ih[64 + j]  + b_hh[64 + j];
    const float bin = b_ih[128 + j];
    const float bhn = b_hh[128 + j];

    __syncthreads();

    for (int t = 0; t < T_; ++t) {
        // ---- stage x_t tile: 32 samples x 32 channels, transposed to [c][s]
        {
            const float* xt = x + (((size_t)b * T_ + t) * N_ + n0) * C_;
            float4 v = reinterpret_cast<const float4*>(xt)[tid];
            int s  = tid >> 3;
            int c0 = (tid & 7) << 2;
            xbuf[(c0 + 0)*SPB + s] = v.x;
            xbuf[(c0 + 1)*SPB + s] = v.y;
            xbuf[(c0 + 2)*SPB + s] = v.z;
            xbuf[(c0 + 3)*SPB + s] = v.w;
        }
        __syncthreads();   // stage visible; prev-step h writes visible

        float ar[8], az[8], ain[8], ahn[8], hprev[8];
        #pragma unroll
        for (int s = 0; s < 8; ++s) { ar[s]=br; az[s]=bz; ain[s]=bin; ahn[s]=bhn; }

        // previous h for this (j, sample group) — own values
        {
            float4 h0 = *reinterpret_cast<const float4*>(&hbuf[j*SPB + s0]);
            float4 h1 = *reinterpret_cast<const float4*>(&hbuf[j*SPB + s0 + 4]);
            hprev[0]=h0.x; hprev[1]=h0.y; hprev[2]=h0.z; hprev[3]=h0.w;
            hprev[4]=h1.x; hprev[5]=h1.y; hprev[6]=h1.z; hprev[7]=h1.w;
        }

        // ---- input contribution: k over 32 channels
        #pragma unroll 4
        for (int k = 0; k < 32; ++k) {
            float wr = wih[k*192 + j];
            float wz = wih[k*192 + 64 + j];
            float wn = wih[k*192 + 128 + j];
            float4 xa = *reinterpret_cast<const float4*>(&xbuf[k*SPB + s0]);
            float4 xb = *reinterpret_cast<const float4*>(&xbuf[k*SPB + s0 + 4]);
            float xv[8] = {xa.x, xa.y, xa.z, xa.w, xb.x, xb.y, xb.z, xb.w};
            #pragma unroll
            for (int s = 0; s < 8; ++s) {
                ar[s]  = fmaf(wr, xv[s], ar[s]);
                az[s]  = fmaf(wz, xv[s], az[s]);
                ain[s] = fmaf(wn, xv[s], ain[s]);
            }
        }

        // ---- hidden contribution: k over 64 hidden units
        #pragma unroll 4
        for (int k = 0; k < 64; ++k) {
            float wr = whh[k*192 + j];
            float wz = whh[k*192 + 64 + j];
            float wn = whh[k*192 + 128 + j];
            float4 ha = *reinterpret_cast<const float4*>(&hbuf[k*SPB + s0]);
            float4 hb = *reinterpret_cast<const float4*>(&hbuf[k*SPB + s0 + 4]);
            float hv[8] = {ha.x, ha.y, ha.z, ha.w, hb.x, hb.y, hb.z, hb.w};
            #pragma unroll
            for (int s = 0; s < 8; ++s) {
                ar[s]  = fmaf(wr, hv[s], ar[s]);
                az[s]  = fmaf(wz, hv[s], az[s]);
                ahn[s] = fmaf(wn, hv[s], ahn[s]);
            }
        }

        __syncthreads();   // all reads of hbuf done

        #pragma unroll
        for (int s = 0; s < 8; ++s) {
            float r  = 1.f / (1.f + expf(-ar[s]));
            float z  = 1.f / (1.f + expf(-az[s]));
            float nn = tanhf(ain[s] + r * ahn[s]);
            float hn = (1.f - z) * nn + z * hprev[s];
            hbuf[j*SPB + s0 + s] = hn;
        }
        // no barrier needed here: next x-stage writes a different array;
        // the barrier after staging orders h writes vs next reads.
    }

    // write final hidden state (own values, no barrier needed)
    #pragma unroll
    for (int s = 0; s < 8; ++s) {
        h_last[(size_t)(m0 + s0 + s) * H_ + j] = hbuf[j*SPB + s0 + s];
    }
}

// key/query projections: one wave per sample
__global__ __launch_bounds__(256) void kq_kernel(
    const float* __restrict__ h, const float* __restrict__ wk,
    const float* __restrict__ wq, float* __restrict__ key, float* __restrict__ query)
{
    int wave = (blockIdx.x * 256 + threadIdx.x) >> 6;
    int lane = threadIdx.x & 63;
    float hv = h[(size_t)wave * 64 + lane];
    float kv = hv * wk[lane];
    float qv = hv * wq[lane];
    #pragma unroll
    for (int off = 32; off; off >>= 1) {
        kv += __shfl_down(kv, off);
        qv += __shfl_down(qv, off);
    }
    if (lane == 0) { key[wave] = kv; query[wave] = qv; }
}

__global__ __launch_bounds__(256) void qmax_kernel(const float* __restrict__ query,
                                                   float* __restrict__ qmax)
{
    int b = blockIdx.x, tid = threadIdx.x;
    float m = -INFINITY;
    for (int i = tid; i < N_; i += 256) m = fmaxf(m, query[b*N_ + i]);
    #pragma unroll
    for (int off = 32; off; off >>= 1) m = fmaxf(m, __shfl_down(m, off));
    __shared__ float sm[4];
    if ((tid & 63) == 0) sm[tid >> 6] = m;
    __syncthreads();
    if (tid == 0) qmax[b] = fmaxf(fmaxf(sm[0], sm[1]), fmaxf(sm[2], sm[3]));
}

// softmax denominators: one wave per (b, row)
__global__ __launch_bounds__(256) void den_kernel(
    const float* __restrict__ key, const float* __restrict__ query,
    const float* __restrict__ qmax, float* __restrict__ den)
{
    int idx  = (blockIdx.x * 256 + threadIdx.x) >> 6;   // b*2048 + i
    int lane = threadIdx.x & 63;
    int b    = idx >> 11;
    float ki = key[idx];
    float mrow = lrelu(ki + qmax[b]);
    const float* q = query + ((size_t)b << 11);
    float sum = 0.f;
    for (int jj = lane; jj < N_; jj += 64)
        sum += expf(lrelu(ki + q[jj]) - mrow);
    #pragma unroll
    for (int off = 32; off; off >>= 1) sum += __shfl_down(sum, off);
    if (lane == 0) den[idx] = sum;
}

// adj[i][j] = 0.125 * sum_b (attn[b][i][j] + attn[b][j][i])
__global__ __launch_bounds__(256) void out_kernel(
    const float* __restrict__ key, const float* __restrict__ query,
    const float* __restrict__ qmax, const float* __restrict__ den,
    float* __restrict__ out)
{
    int flat = blockIdx.x * 256 + threadIdx.x;
    int i = flat >> 11, j = flat & 2047;
    float acc = 0.f;
    #pragma unroll
    for (int b = 0; b < B_; ++b) {
        int bi = (b << 11) + i, bj = (b << 11) + j;
        float ki = key[bi], kj = key[bj];
        float qi = query[bi], qj = query[bj];
        float qm = qmax[b];
        float mi = lrelu(ki + qm), mj = lrelu(kj + qm);
        float aij = expf(lrelu(ki + qj) - mi) / den[bi];
        float aji = expf(lrelu(kj + qi) - mj) / den[bj];
        acc += aij + aji;
    }
    out[flat] = 0.125f * acc;
}

extern "C" void kernel_launch(void* const* d_in, const int* in_sizes, int n_in,
                              void* d_out, int out_size, void* d_ws, size_t ws_size,
                              hipStream_t stream) {
    const float* x    = (const float*)d_in[0];
    const float* w_ih = (const float*)d_in[1];
    const float* w_hh = (const float*)d_in[2];
    const float* b_ih = (const float*)d_in[3];
    const float* b_hh = (const float*)d_in[4];
    const float* wk   = (const float*)d_in[5];
    const float* wq   = (const float*)d_in[6];
    float* out = (float*)d_out;
    float* ws  = (float*)d_ws;

    // Bulk scratch (h_last, 2 MB) lives in d_out: it is dead before out_kernel
    // (the final launch) overwrites the entire 16 MB output. Only 96 KB of
    // small arrays live in d_ws — no assumption of a large workspace.
    float* h_last = out;                      // [0, 524288) floats of d_out
    float* key    = ws;                       // 8192
    float* query  = ws + 8192;                // 8192
    float* qmax   = ws + 16384;               // 4
    float* den    = ws + 16388;               // 8192   (total 24580 floats = 96.1 KB)

    hipFuncSetAttribute((const void*)gru_kernel,
                        hipFuncAttributeMaxDynamicSharedMemorySize, LDS_BYTES);

    gru_kernel<<<M_/SPB, 256, LDS_BYTES, stream>>>(x, w_ih, w_hh, b_ih, b_hh, h_last);
    kq_kernel<<<M_/4, 256, 0, stream>>>(h_last, wk, wq, key, query);
    qmax_kernel<<<B_, 256, 0, stream>>>(query, qmax);
    den_kernel<<<M_/4, 256, 0, stream>>>(key, query, qmax, den);
    out_kernel<<<(N_*N_)/256, 256, 0, stream>>>(key, query, qmax, den, out);
}

// Round 3
// 388.814 us; speedup vs baseline: 1.7592x; 1.7592x over previous
//
#include <hip/hip_runtime.h>
#include <math.h>

#define B_ 4
#define T_ 64
#define N_ 2048
#define C_ 32
#define H_ 64
#define M_ (B_*N_)      // 8192
#define SPB 16          // samples per GRU block
#define SLOPE 0.2f

// Dynamic LDS layout (floats):
//   whh : [64][192]   k-major transposed W_hh          12288
//   wih : [32][192]   k-major transposed W_ih           6144
//   hbuf: [SPB][64]   sample-major hidden state         1024
//   xbuf: [SPB][32]   sample-major current x tile        512
// total 19968 floats = 79872 B  -> 2 blocks/CU (159744 <= 163840)
#define LDS_FLOATS (64*192 + 32*192 + SPB*64 + SPB*32)
#define LDS_BYTES (LDS_FLOATS*4)

__device__ __forceinline__ float lrelu(float v) { return v >= 0.f ? v : SLOPE * v; }
// sigmoid: 1/(1+e^-x); x->-inf: e^-x=inf -> 0 ; x->+inf: -> 1   (correct limits)
__device__ __forceinline__ float fsig(float x)  { return 1.f / (1.f + __expf(-x)); }
// tanh = 1 - 2/(e^{2x}+1); x->+inf: 1 ; x->-inf: -1              (correct limits)
__device__ __forceinline__ float ftanh(float x) { return 1.f - 2.f / (__expf(2.f * x) + 1.f); }

extern __shared__ float lds[];

__global__ __launch_bounds__(256) void gru_kernel(
    const float* __restrict__ x,      // [B,T,N,C]
    const float* __restrict__ w_ih,   // [192][32]
    const float* __restrict__ w_hh,   // [192][64]
    const float* __restrict__ b_ih,   // [192]
    const float* __restrict__ b_hh,   // [192]
    float* __restrict__ h_last)       // [M][H]  (lives in d_out scratch)
{
    float* whh  = lds;                    // [64][192]
    float* wih  = lds + 64*192;           // [32][192]
    float* hbuf = lds + 96*192;           // [SPB][64]
    float* xbuf = hbuf + SPB*64;          // [SPB][32]

    const int tid = threadIdx.x;
    const int j   = tid & 63;             // hidden index (lane)
    const int sg  = tid >> 6;             // sample group 0..3
    const int s0  = sg * 4;               // 4 samples per thread

    const int m0 = blockIdx.x * SPB;      // first sample of block
    const int b  = m0 >> 11;              // /2048
    const int n0 = m0 & 2047;

    // Stage W transposed into LDS (once)
    for (int idx = tid; idx < 192*64; idx += 256) {
        int jp = idx >> 6, k = idx & 63;
        whh[k*192 + jp] = w_hh[idx];
    }
    for (int idx = tid; idx < 192*32; idx += 256) {
        int jp = idx >> 5, k = idx & 31;
        wih[k*192 + jp] = w_ih[idx];
    }
    for (int idx = tid; idx < SPB*64; idx += 256) hbuf[idx] = 0.f;

    const float br  = b_ih[j]       + b_hh[j];
    const float bz  = b_ih[64 + j]  + b_hh[64 + j];
    const float bin = b_ih[128 + j];
    const float bhn = b_hh[128 + j];

    __syncthreads();

    const float4* xt4base = reinterpret_cast<const float4*>(
        x + (((size_t)b * T_) * N_ + n0) * C_);
    float4* xb4 = reinterpret_cast<float4*>(xbuf);

    for (int t = 0; t < T_; ++t) {
        // ---- stage x_t tile: SPB*32 floats, contiguous copy (128 float4)
        if (tid < SPB*32/4) {
            xb4[tid] = xt4base[(size_t)t * (N_*C_/4) + tid];
        }
        __syncthreads();   // x staged; prev-step h writes visible

        float ar[4], az[4], ain[4], ahn[4], hprev[4];
        #pragma unroll
        for (int s = 0; s < 4; ++s) {
            ar[s]=br; az[s]=bz; ain[s]=bin; ahn[s]=bhn;
            hprev[s] = hbuf[(s0+s)*64 + j];            // lane-stride-1, conflict-free
        }

        // ---- input contribution: k over 32 channels (wave-uniform x broadcasts)
        #pragma unroll
        for (int kg = 0; kg < 32; kg += 4) {
            float4 xv0 = *reinterpret_cast<const float4*>(&xbuf[(s0+0)*32 + kg]);
            float4 xv1 = *reinterpret_cast<const float4*>(&xbuf[(s0+1)*32 + kg]);
            float4 xv2 = *reinterpret_cast<const float4*>(&xbuf[(s0+2)*32 + kg]);
            float4 xv3 = *reinterpret_cast<const float4*>(&xbuf[(s0+3)*32 + kg]);
            #pragma unroll
            for (int kk = 0; kk < 4; ++kk) {
                int k = kg + kk;
                float wr = wih[k*192 + j];
                float wz = wih[k*192 + 64 + j];
                float wn = wih[k*192 + 128 + j];
                float xs0 = (&xv0.x)[kk], xs1 = (&xv1.x)[kk];
                float xs2 = (&xv2.x)[kk], xs3 = (&xv3.x)[kk];
                ar[0]=fmaf(wr,xs0,ar[0]); az[0]=fmaf(wz,xs0,az[0]); ain[0]=fmaf(wn,xs0,ain[0]);
                ar[1]=fmaf(wr,xs1,ar[1]); az[1]=fmaf(wz,xs1,az[1]); ain[1]=fmaf(wn,xs1,ain[1]);
                ar[2]=fmaf(wr,xs2,ar[2]); az[2]=fmaf(wz,xs2,az[2]); ain[2]=fmaf(wn,xs2,ain[2]);
                ar[3]=fmaf(wr,xs3,ar[3]); az[3]=fmaf(wz,xs3,az[3]); ain[3]=fmaf(wn,xs3,ain[3]);
            }
        }

        // ---- hidden contribution: k over 64 hidden units (wave-uniform h broadcasts)
        #pragma unroll
        for (int kg = 0; kg < 64; kg += 4) {
            float4 hv0 = *reinterpret_cast<const float4*>(&hbuf[(s0+0)*64 + kg]);
            float4 hv1 = *reinterpret_cast<const float4*>(&hbuf[(s0+1)*64 + kg]);
            float4 hv2 = *reinterpret_cast<const float4*>(&hbuf[(s0+2)*64 + kg]);
            float4 hv3 = *reinterpret_cast<const float4*>(&hbuf[(s0+3)*64 + kg]);
            #pragma unroll
            for (int kk = 0; kk < 4; ++kk) {
                int k = kg + kk;
                float wr = whh[k*192 + j];
                float wz = whh[k*192 + 64 + j];
                float wn = whh[k*192 + 128 + j];
                float hs0 = (&hv0.x)[kk], hs1 = (&hv1.x)[kk];
                float hs2 = (&hv2.x)[kk], hs3 = (&hv3.x)[kk];
                ar[0]=fmaf(wr,hs0,ar[0]); az[0]=fmaf(wz,hs0,az[0]); ahn[0]=fmaf(wn,hs0,ahn[0]);
                ar[1]=fmaf(wr,hs1,ar[1]); az[1]=fmaf(wz,hs1,az[1]); ahn[1]=fmaf(wn,hs1,ahn[1]);
                ar[2]=fmaf(wr,hs2,ar[2]); az[2]=fmaf(wz,hs2,az[2]); ahn[2]=fmaf(wn,hs2,ahn[2]);
                ar[3]=fmaf(wr,hs3,ar[3]); az[3]=fmaf(wz,hs3,az[3]); ahn[3]=fmaf(wn,hs3,ahn[3]);
            }
        }

        __syncthreads();   // all reads of hbuf/xbuf done

        #pragma unroll
        for (int s = 0; s < 4; ++s) {
            float r  = fsig(ar[s]);
            float z  = fsig(az[s]);
            float nn = ftanh(ain[s] + r * ahn[s]);
            float hn = (1.f - z) * nn + z * hprev[s];
            hbuf[(s0+s)*64 + j] = hn;                  // lane-stride-1, conflict-free
        }
        // barrier at top of next iteration orders these writes vs next reads
    }

    // write final hidden state
    #pragma unroll
    for (int s = 0; s < 4; ++s) {
        h_last[(size_t)(m0 + s0 + s) * H_ + j] = hbuf[(s0+s)*64 + j];
    }
}

// key/query projections: one wave per sample
__global__ __launch_bounds__(256) void kq_kernel(
    const float* __restrict__ h, const float* __restrict__ wk,
    const float* __restrict__ wq, float* __restrict__ key, float* __restrict__ query)
{
    int wave = (blockIdx.x * 256 + threadIdx.x) >> 6;
    int lane = threadIdx.x & 63;
    float hv = h[(size_t)wave * 64 + lane];
    float kv = hv * wk[lane];
    float qv = hv * wq[lane];
    #pragma unroll
    for (int off = 32; off; off >>= 1) {
        kv += __shfl_down(kv, off);
        qv += __shfl_down(qv, off);
    }
    if (lane == 0) { key[wave] = kv; query[wave] = qv; }
}

__global__ __launch_bounds__(256) void qmax_kernel(const float* __restrict__ query,
                                                   float* __restrict__ qmax)
{
    int b = blockIdx.x, tid = threadIdx.x;
    float m = -INFINITY;
    for (int i = tid; i < N_; i += 256) m = fmaxf(m, query[b*N_ + i]);
    #pragma unroll
    for (int off = 32; off; off >>= 1) m = fmaxf(m, __shfl_down(m, off));
    __shared__ float sm[4];
    if ((tid & 63) == 0) sm[tid >> 6] = m;
    __syncthreads();
    if (tid == 0) qmax[b] = fmaxf(fmaxf(sm[0], sm[1]), fmaxf(sm[2], sm[3]));
}

// softmax denominators: one wave per (b, row)
__global__ __launch_bounds__(256) void den_kernel(
    const float* __restrict__ key, const float* __restrict__ query,
    const float* __restrict__ qmax, float* __restrict__ den)
{
    int idx  = (blockIdx.x * 256 + threadIdx.x) >> 6;   // b*2048 + i
    int lane = threadIdx.x & 63;
    int b    = idx >> 11;
    float ki = key[idx];
    float mrow = lrelu(ki + qmax[b]);
    const float* q = query + ((size_t)b << 11);
    float sum = 0.f;
    for (int jj = lane; jj < N_; jj += 64)
        sum += __expf(lrelu(ki + q[jj]) - mrow);
    #pragma unroll
    for (int off = 32; off; off >>= 1) sum += __shfl_down(sum, off);
    if (lane == 0) den[idx] = sum;
}

// adj[i][j] = 0.125 * sum_b (attn[b][i][j] + attn[b][j][i])
__global__ __launch_bounds__(256) void out_kernel(
    const float* __restrict__ key, const float* __restrict__ query,
    const float* __restrict__ qmax, const float* __restrict__ den,
    float* __restrict__ out)
{
    int flat = blockIdx.x * 256 + threadIdx.x;
    int i = flat >> 11, j = flat & 2047;
    float acc = 0.f;
    #pragma unroll
    for (int b = 0; b < B_; ++b) {
        int bi = (b << 11) + i, bj = (b << 11) + j;
        float ki = key[bi], kj = key[bj];
        float qi = query[bi], qj = query[bj];
        float qm = qmax[b];
        float mi = lrelu(ki + qm), mj = lrelu(kj + qm);
        float aij = __expf(lrelu(ki + qj) - mi) / den[bi];
        float aji = __expf(lrelu(kj + qi) - mj) / den[bj];
        acc += aij + aji;
    }
    out[flat] = 0.125f * acc;
}

extern "C" void kernel_launch(void* const* d_in, const int* in_sizes, int n_in,
                              void* d_out, int out_size, void* d_ws, size_t ws_size,
                              hipStream_t stream) {
    const float* x    = (const float*)d_in[0];
    const float* w_ih = (const float*)d_in[1];
    const float* w_hh = (const float*)d_in[2];
    const float* b_ih = (const float*)d_in[3];
    const float* b_hh = (const float*)d_in[4];
    const float* wk   = (const float*)d_in[5];
    const float* wq   = (const float*)d_in[6];
    float* out = (float*)d_out;
    float* ws  = (float*)d_ws;

    // Bulk scratch (h_last, 2 MB) lives in d_out: dead before out_kernel
    // (the final launch) overwrites the entire 16 MB output.
    float* h_last = out;                      // [0, 524288) floats of d_out
    float* key    = ws;                       // 8192
    float* query  = ws + 8192;                // 8192
    float* qmax   = ws + 16384;               // 4
    float* den    = ws + 16388;               // 8192

    hipFuncSetAttribute((const void*)gru_kernel,
                        hipFuncAttributeMaxDynamicSharedMemorySize, LDS_BYTES);

    gru_kernel<<<M_/SPB, 256, LDS_BYTES, stream>>>(x, w_ih, w_hh, b_ih, b_hh, h_last);
    kq_kernel<<<M_/4, 256, 0, stream>>>(h_last, wk, wq, key, query);
    qmax_kernel<<<B_, 256, 0, stream>>>(query, qmax);
    den_kernel<<<M_/4, 256, 0, stream>>>(key, query, qmax, den);
    out_kernel<<<(N_*N_)/256, 256, 0, stream>>>(key, query, qmax, den, out);
}

// Round 4
// 133.486 us; speedup vs baseline: 5.1243x; 2.9128x over previous
//
#include <hip/hip_runtime.h>
#include <math.h>

#define B_ 4
#define T_ 64
#define N_ 2048
#define C_ 32
#define H_ 64
#define M_ (B_*N_)      // 8192
#define SPB 16          // samples per GRU block (one 16-row M-tile)
#define SLOPE 0.2f

typedef __attribute__((ext_vector_type(8))) short short8;   // 8 bf16 (4 VGPRs)
typedef __attribute__((ext_vector_type(4))) float floatx4;  // MFMA acc

#define MFMA16(a,b,c) __builtin_amdgcn_mfma_f32_16x16x32_bf16(a,b,c,0,0,0)

__device__ __forceinline__ float lrelu(float v) { return v >= 0.f ? v : SLOPE * v; }
__device__ __forceinline__ float fsig(float x)  { return 1.f / (1.f + __expf(-x)); }
__device__ __forceinline__ float ftanh(float x) { return 1.f - 2.f / (__expf(2.f * x) + 1.f); }

__device__ __forceinline__ unsigned short bf16_rtn(float f) {
    unsigned u = __float_as_uint(f);
    return (unsigned short)((u + 0x7fffu + ((u >> 16) & 1u)) >> 16);
}
__device__ __forceinline__ float bf16_f32(unsigned short s) {
    return __uint_as_float(((unsigned)s) << 16);
}
__device__ __forceinline__ void split2(float f, unsigned short& h, unsigned short& l) {
    h = bf16_rtn(f);
    l = bf16_rtn(f - bf16_f32(h));
}

// LDS (shorts): [hb_hi b0 | hb_hi b1 | hb_lo b0 | hb_lo b1 | xb_hi b0 | xb_hi b1 | xb_lo b0 | xb_lo b1]
#define HB_SZ (16*64)   // 1024 shorts = 2 KB per component per buffer
#define XB_SZ (64*8)    //  512 shorts = 1 KB per component per buffer
// total = 4*HB_SZ + 4*XB_SZ = 6144 shorts = 12 KB

__global__ __launch_bounds__(256, 2) void gru_kernel(
    const float* __restrict__ x,      // [B,T,N,C]
    const float* __restrict__ w_ih,   // [192][32]
    const float* __restrict__ w_hh,   // [192][64]
    const float* __restrict__ b_ih,   // [192]
    const float* __restrict__ b_hh,   // [192]
    float* __restrict__ h_last)       // [M][H]  (d_out scratch)
{
    __shared__ short smem[4*HB_SZ + 4*XB_SZ];

    const int tid   = threadIdx.x;
    const int lane  = tid & 63;
    const int w     = tid >> 6;        // wave 0..3 -> owns N-tiles {w, w+4, w+8}
    const int col16 = lane & 15;       // A-row / B-col / C-col within tile
    const int kgrp  = lane >> 4;       // 0..3 (k-group of 8)

    const int m0 = blockIdx.x * SPB;
    const int b  = m0 >> 11;
    const int n0 = m0 & 2047;

    // ---- weight B-fragments -> registers (once). B[k][col] = w[col][k]. ----
    short8 whh_hi[3][2], whh_lo[3][2], wih_hi[3], wih_lo[3];
    #pragma unroll
    for (int g = 0; g < 3; ++g) {
        const int colj = g*64 + w*16 + col16;        // gate row in [0,192)
        #pragma unroll
        for (int kb = 0; kb < 2; ++kb) {
            const float* src = w_hh + colj*64 + kb*32 + kgrp*8;
            short8 hi, lo;
            #pragma unroll
            for (int e = 0; e < 8; ++e) {
                unsigned short h_, l_; split2(src[e], h_, l_);
                hi[e] = (short)h_; lo[e] = (short)l_;
            }
            whh_hi[g][kb] = hi; whh_lo[g][kb] = lo;
        }
        {
            const float* src = w_ih + colj*32 + kgrp*8;
            short8 hi, lo;
            #pragma unroll
            for (int e = 0; e < 8; ++e) {
                unsigned short h_, l_; split2(src[e], h_, l_);
                hi[e] = (short)h_; lo[e] = (short)l_;
            }
            wih_hi[g] = hi; wih_lo[g] = lo;
        }
    }

    const int jcol = w*16 + col16;     // hidden index this lane owns (0..63)
    const float br  = b_ih[jcol]       + b_hh[jcol];
    const float bz  = b_ih[64 + jcol]  + b_hh[64 + jcol];
    const float bin = b_ih[128 + jcol];
    const float bhn = b_hh[128 + jcol];

    // ---- prologue: zero h buf0 (hi+lo); stage x[0] fragments into x buf0 ----
    for (int i = tid; i < HB_SZ; i += 256) { smem[i] = 0; smem[2*HB_SZ + i] = 0; }
    {
        const int fl = tid >> 2;                  // frag-lane 0..63
        const int e0 = (tid & 3) * 2;             // element pair
        const int row = fl & 15;
        const int kk  = (fl >> 4) * 8 + e0;
        const float* xs = x + (((size_t)b * T_) * N_ + (n0 + row)) * C_ + kk;
        unsigned short h0,l0,h1,l1;
        split2(xs[0], h0, l0); split2(xs[1], h1, l1);
        const int ii = fl*4 + (tid & 3);
        ((int*)(smem + 4*HB_SZ))[ii]            = (int)h0 | ((int)h1 << 16);
        ((int*)(smem + 4*HB_SZ + 2*XB_SZ))[ii]  = (int)l0 | ((int)l1 << 16);
    }
    __syncthreads();

    float hprev[4] = {0.f, 0.f, 0.f, 0.f};

    for (int t = 0; t < T_; ++t) {
        const int cur = t & 1, nxt = cur ^ 1;
        const short* hbh = smem + cur*HB_SZ;
        const short* hbl = smem + 2*HB_SZ + cur*HB_SZ;
        const short* xbh = smem + 4*HB_SZ + cur*XB_SZ;
        const short* xbl = smem + 4*HB_SZ + 2*XB_SZ + cur*XB_SZ;

        // ---- A fragments: h (swizzled [16][64]) and x (frag-linear) ----
        short8 ah_hi[2], ah_lo[2];
        #pragma unroll
        for (int kb = 0; kb < 2; ++kb) {
            const int kidx = kgrp*8 + kb*32;
            const int idx  = col16*64 + (kidx ^ ((col16 & 7) << 3));
            ah_hi[kb] = *(const short8*)(hbh + idx);
            ah_lo[kb] = *(const short8*)(hbl + idx);
        }
        const short8 ax_hi = *(const short8*)(xbh + lane*8);
        const short8 ax_lo = *(const short8*)(xbl + lane*8);

        // ---- prefetch x for t+1 (global, 2 floats/thread) ----
        float f0 = 0.f, f1 = 0.f;
        const int fl = tid >> 2, e0p = (tid & 3) * 2;
        if (t + 1 < T_) {
            const int row = fl & 15, kk = (fl >> 4) * 8 + e0p;
            const float* xs = x + (((size_t)b*T_ + (t+1))*N_ + (n0 + row))*C_ + kk;
            f0 = xs[0]; f1 = xs[1];
        }

        // ---- MFMAs: 3-product split (hi*hi + hi*lo + lo*hi) ----
        floatx4 accR  = {br, br, br, br};
        floatx4 accZ  = {bz, bz, bz, bz};
        floatx4 accIN = {bin, bin, bin, bin};
        floatx4 accHN = {bhn, bhn, bhn, bhn};

        // input projection (K=32)
        accR  = MFMA16(ax_hi, wih_hi[0], accR);
        accR  = MFMA16(ax_hi, wih_lo[0], accR);
        accR  = MFMA16(ax_lo, wih_hi[0], accR);
        accZ  = MFMA16(ax_hi, wih_hi[1], accZ);
        accZ  = MFMA16(ax_hi, wih_lo[1], accZ);
        accZ  = MFMA16(ax_lo, wih_hi[1], accZ);
        accIN = MFMA16(ax_hi, wih_hi[2], accIN);
        accIN = MFMA16(ax_hi, wih_lo[2], accIN);
        accIN = MFMA16(ax_lo, wih_hi[2], accIN);
        // hidden projection (K=64 = 2 blocks)
        #pragma unroll
        for (int kb = 0; kb < 2; ++kb) {
            accR  = MFMA16(ah_hi[kb], whh_hi[0][kb], accR);
            accR  = MFMA16(ah_hi[kb], whh_lo[0][kb], accR);
            accR  = MFMA16(ah_lo[kb], whh_hi[0][kb], accR);
            accZ  = MFMA16(ah_hi[kb], whh_hi[1][kb], accZ);
            accZ  = MFMA16(ah_hi[kb], whh_lo[1][kb], accZ);
            accZ  = MFMA16(ah_lo[kb], whh_hi[1][kb], accZ);
            accHN = MFMA16(ah_hi[kb], whh_hi[2][kb], accHN);
            accHN = MFMA16(ah_hi[kb], whh_lo[2][kb], accHN);
            accHN = MFMA16(ah_lo[kb], whh_hi[2][kb], accHN);
        }

        // ---- convert + store x frags for t+1 ----
        if (t + 1 < T_) {
            unsigned short h0,l0,h1,l1;
            split2(f0, h0, l0); split2(f1, h1, l1);
            const int ii = fl*4 + (tid & 3);
            ((int*)(smem + 4*HB_SZ + nxt*XB_SZ))[ii]           = (int)h0 | ((int)h1 << 16);
            ((int*)(smem + 4*HB_SZ + 2*XB_SZ + nxt*XB_SZ))[ii] = (int)l0 | ((int)l1 << 16);
        }

        // ---- activations (lane-local), h update, store split h for t+1 ----
        short* nhh = smem + nxt*HB_SZ;
        short* nhl = smem + 2*HB_SZ + nxt*HB_SZ;
        #pragma unroll
        for (int s = 0; s < 4; ++s) {
            const float r  = fsig(accR[s]);
            const float z  = fsig(accZ[s]);
            const float nn = ftanh(accIN[s] + r * accHN[s]);
            const float h  = (1.f - z) * nn + z * hprev[s];
            hprev[s] = h;
            const int smp = kgrp*4 + s;              // C-frag row = sample
            unsigned short hh, hl; split2(h, hh, hl);
            const int idx = smp*64 + (jcol ^ ((smp & 7) << 3));
            nhh[idx] = (short)hh;
            nhl[idx] = (short)hl;
        }
        __syncthreads();
    }

    // ---- write final hidden state (fp32 exact from registers) ----
    #pragma unroll
    for (int s = 0; s < 4; ++s) {
        const int smp = kgrp*4 + s;
        h_last[(size_t)(m0 + smp)*H_ + jcol] = hprev[s];
    }
}

// key/query projections: one wave per sample
__global__ __launch_bounds__(256) void kq_kernel(
    const float* __restrict__ h, const float* __restrict__ wk,
    const float* __restrict__ wq, float* __restrict__ key, float* __restrict__ query)
{
    int wave = (blockIdx.x * 256 + threadIdx.x) >> 6;
    int lane = threadIdx.x & 63;
    float hv = h[(size_t)wave * 64 + lane];
    float kv = hv * wk[lane];
    float qv = hv * wq[lane];
    #pragma unroll
    for (int off = 32; off; off >>= 1) {
        kv += __shfl_down(kv, off);
        qv += __shfl_down(qv, off);
    }
    if (lane == 0) { key[wave] = kv; query[wave] = qv; }
}

__global__ __launch_bounds__(256) void qmax_kernel(const float* __restrict__ query,
                                                   float* __restrict__ qmax)
{
    int b = blockIdx.x, tid = threadIdx.x;
    float m = -INFINITY;
    for (int i = tid; i < N_; i += 256) m = fmaxf(m, query[b*N_ + i]);
    #pragma unroll
    for (int off = 32; off; off >>= 1) m = fmaxf(m, __shfl_down(m, off));
    __shared__ float sm[4];
    if ((tid & 63) == 0) sm[tid >> 6] = m;
    __syncthreads();
    if (tid == 0) qmax[b] = fmaxf(fmaxf(sm[0], sm[1]), fmaxf(sm[2], sm[3]));
}

// softmax denominators: one wave per (b, row)
__global__ __launch_bounds__(256) void den_kernel(
    const float* __restrict__ key, const float* __restrict__ query,
    const float* __restrict__ qmax, float* __restrict__ den)
{
    int idx  = (blockIdx.x * 256 + threadIdx.x) >> 6;   // b*2048 + i
    int lane = threadIdx.x & 63;
    int b    = idx >> 11;
    float ki = key[idx];
    float mrow = lrelu(ki + qmax[b]);
    const float* q = query + ((size_t)b << 11);
    float sum = 0.f;
    for (int jj = lane; jj < N_; jj += 64)
        sum += __expf(lrelu(ki + q[jj]) - mrow);
    #pragma unroll
    for (int off = 32; off; off >>= 1) sum += __shfl_down(sum, off);
    if (lane == 0) den[idx] = sum;
}

// adj[i][j] = 0.125 * sum_b (attn[b][i][j] + attn[b][j][i])
__global__ __launch_bounds__(256) void out_kernel(
    const float* __restrict__ key, const float* __restrict__ query,
    const float* __restrict__ qmax, const float* __restrict__ den,
    float* __restrict__ out)
{
    int flat = blockIdx.x * 256 + threadIdx.x;
    int i = flat >> 11, j = flat & 2047;
    float acc = 0.f;
    #pragma unroll
    for (int b = 0; b < B_; ++b) {
        int bi = (b << 11) + i, bj = (b << 11) + j;
        float ki = key[bi], kj = key[bj];
        float qi = query[bi], qj = query[bj];
        float qm = qmax[b];
        float mi = lrelu(ki + qm), mj = lrelu(kj + qm);
        float aij = __expf(lrelu(ki + qj) - mi) / den[bi];
        float aji = __expf(lrelu(kj + qi) - mj) / den[bj];
        acc += aij + aji;
    }
    out[flat] = 0.125f * acc;
}

extern "C" void kernel_launch(void* const* d_in, const int* in_sizes, int n_in,
                              void* d_out, int out_size, void* d_ws, size_t ws_size,
                              hipStream_t stream) {
    const float* x    = (const float*)d_in[0];
    const float* w_ih = (const float*)d_in[1];
    const float* w_hh = (const float*)d_in[2];
    const float* b_ih = (const float*)d_in[3];
    const float* b_hh = (const float*)d_in[4];
    const float* wk   = (const float*)d_in[5];
    const float* wq   = (const float*)d_in[6];
    float* out = (float*)d_out;
    float* ws  = (float*)d_ws;

    // Bulk scratch (h_last, 2 MB) lives in d_out: dead before out_kernel
    // (the final launch) overwrites the entire 16 MB output.
    float* h_last = out;                      // [0, 524288) floats of d_out
    float* key    = ws;                       // 8192
    float* query  = ws + 8192;                // 8192
    float* qmax   = ws + 16384;               // 4
    float* den    = ws + 16388;               // 8192

    gru_kernel<<<M_/SPB, 256, 0, stream>>>(x, w_ih, w_hh, b_ih, b_hh, h_last);
    kq_kernel<<<M_/4, 256, 0, stream>>>(h_last, wk, wq, key, query);
    qmax_kernel<<<B_, 256, 0, stream>>>(query, qmax);
    den_kernel<<<M_/4, 256, 0, stream>>>(key, query, qmax, den);
    out_kernel<<<(N_*N_)/256, 256, 0, stream>>>(key, query, qmax, den, out);
}

// Round 5
// 133.349 us; speedup vs baseline: 5.1295x; 1.0010x over previous
//
#include <hip/hip_runtime.h>
#include <math.h>

#define B_ 4
#define T_ 64
#define N_ 2048
#define C_ 32
#define H_ 64
#define M_ (B_*N_)      // 8192
#define SPB 16          // samples per GRU block (one 16-row M-tile)
#define SLOPE 0.2f

typedef __attribute__((ext_vector_type(8))) short short8;   // 8 bf16 (4 VGPRs)
typedef __attribute__((ext_vector_type(4))) float floatx4;  // MFMA acc

#define MFMA16(a,b,c) __builtin_amdgcn_mfma_f32_16x16x32_bf16(a,b,c,0,0,0)

// Barrier that does NOT drain vmcnt: LDS visibility via lgkmcnt(0), global
// prefetch loads stay in flight across the barrier (compiler's __syncthreads
// would emit s_waitcnt vmcnt(0) and serialize the x prefetch every step).
// Control flow reaching this is uniform across the block.
#define BARRIER() asm volatile("s_waitcnt lgkmcnt(0)\n\ts_barrier" ::: "memory")

__device__ __forceinline__ float lrelu(float v) { return v >= 0.f ? v : SLOPE * v; }
__device__ __forceinline__ float fsig(float x)  { return 1.f / (1.f + __expf(-x)); }
__device__ __forceinline__ float ftanh(float x) { return 1.f - 2.f / (__expf(2.f * x) + 1.f); }

__device__ __forceinline__ unsigned short bf16_rtn(float f) {
    unsigned u = __float_as_uint(f);
    return (unsigned short)((u + 0x7fffu + ((u >> 16) & 1u)) >> 16);
}
__device__ __forceinline__ float bf16_f32(unsigned short s) {
    return __uint_as_float(((unsigned)s) << 16);
}
__device__ __forceinline__ void split2(float f, unsigned short& h, unsigned short& l) {
    h = bf16_rtn(f);
    l = bf16_rtn(f - bf16_f32(h));
}

// LDS (shorts): [hb_hi b0 | hb_hi b1 | hb_lo b0 | hb_lo b1 | xb_hi b0 | xb_hi b1 | xb_lo b0 | xb_lo b1]
#define HB_SZ (16*64)   // 1024 shorts = 2 KB per component per buffer
#define XB_SZ (64*8)    //  512 shorts = 1 KB per component per buffer

__global__ __launch_bounds__(256, 2) void gru_kernel(
    const float* __restrict__ x,      // [B,T,N,C]
    const float* __restrict__ w_ih,   // [192][32]
    const float* __restrict__ w_hh,   // [192][64]
    const float* __restrict__ b_ih,   // [192]
    const float* __restrict__ b_hh,   // [192]
    float* __restrict__ h_last)       // [M][H]  (d_out scratch)
{
    __shared__ short smem[4*HB_SZ + 4*XB_SZ];

    const int tid   = threadIdx.x;
    const int lane  = tid & 63;
    const int w     = tid >> 6;        // wave 0..3 -> owns N-tiles {w, w+4, w+8}
    const int col16 = lane & 15;
    const int kgrp  = lane >> 4;       // 0..3

    const int m0 = blockIdx.x * SPB;
    const int b  = m0 >> 11;
    const int n0 = m0 & 2047;

    // ---- weight B-fragments -> registers (once). B[k][col] = w[col][k]. ----
    short8 whh_hi[3][2], whh_lo[3][2], wih_hi[3], wih_lo[3];
    #pragma unroll
    for (int g = 0; g < 3; ++g) {
        const int colj = g*64 + w*16 + col16;
        #pragma unroll
        for (int kb = 0; kb < 2; ++kb) {
            const float* src = w_hh + colj*64 + kb*32 + kgrp*8;
            short8 hi, lo;
            #pragma unroll
            for (int e = 0; e < 8; ++e) {
                unsigned short h_, l_; split2(src[e], h_, l_);
                hi[e] = (short)h_; lo[e] = (short)l_;
            }
            whh_hi[g][kb] = hi; whh_lo[g][kb] = lo;
        }
        {
            const float* src = w_ih + colj*32 + kgrp*8;
            short8 hi, lo;
            #pragma unroll
            for (int e = 0; e < 8; ++e) {
                unsigned short h_, l_; split2(src[e], h_, l_);
                hi[e] = (short)h_; lo[e] = (short)l_;
            }
            wih_hi[g] = hi; wih_lo[g] = lo;
        }
    }

    const int jcol = w*16 + col16;
    const float br  = b_ih[jcol]       + b_hh[jcol];
    const float bz  = b_ih[64 + jcol]  + b_hh[64 + jcol];
    const float bin = b_ih[128 + jcol];
    const float bhn = b_hh[128 + jcol];

    // per-thread x staging geometry (2 floats/thread/step)
    const int fl  = tid >> 2;                 // frag-lane 0..63
    const int row = fl & 15;
    const int kk  = (fl >> 4) * 8 + (tid & 3) * 2;
    const int xii = fl*4 + (tid & 3);
    const float* xsrc = x + (((size_t)b * T_) * N_ + (n0 + row)) * C_ + kk;

    // ---- prologue: zero h buf0; stage x(0) into buf0; issue x(1) prefetch ----
    for (int i = tid; i < HB_SZ; i += 256) { smem[i] = 0; smem[2*HB_SZ + i] = 0; }
    {
        unsigned short h0,l0,h1,l1;
        split2(xsrc[0], h0, l0); split2(xsrc[1], h1, l1);
        ((int*)(smem + 4*HB_SZ))[xii]            = (int)h0 | ((int)h1 << 16);
        ((int*)(smem + 4*HB_SZ + 2*XB_SZ))[xii]  = (int)l0 | ((int)l1 << 16);
    }
    float pA0 = xsrc[N_*C_], pA1 = xsrc[N_*C_ + 1];   // x(1)
    float pB0 = 0.f, pB1 = 0.f;
    BARRIER();

    float hprev[4] = {0.f, 0.f, 0.f, 0.f};

#define GRU_STEP(T, CUR, PF0, PF1, PG0, PG1) do {                               \
    const int nxt_ = (CUR) ^ 1;                                                 \
    const short* hbh = smem + (CUR)*HB_SZ;                                      \
    const short* hbl = smem + 2*HB_SZ + (CUR)*HB_SZ;                            \
    const short* xbh = smem + 4*HB_SZ + (CUR)*XB_SZ;                            \
    const short* xbl = smem + 4*HB_SZ + 2*XB_SZ + (CUR)*XB_SZ;                  \
    short8 ah_hi[2], ah_lo[2];                                                  \
    _Pragma("unroll")                                                           \
    for (int kb = 0; kb < 2; ++kb) {                                            \
        const int kidx = kgrp*8 + kb*32;                                        \
        const int idx  = col16*64 + (kidx ^ ((col16 & 7) << 3));                \
        ah_hi[kb] = *(const short8*)(hbh + idx);                                \
        ah_lo[kb] = *(const short8*)(hbl + idx);                                \
    }                                                                           \
    const short8 ax_hi = *(const short8*)(xbh + lane*8);                        \
    const short8 ax_lo = *(const short8*)(xbl + lane*8);                        \
    if ((T) + 1 < T_) {  /* store x(T+1) from regs loaded one step ago */       \
        unsigned short h0,l0,h1,l1;                                             \
        split2(PF0, h0, l0); split2(PF1, h1, l1);                               \
        ((int*)(smem + 4*HB_SZ + nxt_*XB_SZ))[xii]           = (int)h0 | ((int)h1 << 16); \
        ((int*)(smem + 4*HB_SZ + 2*XB_SZ + nxt_*XB_SZ))[xii] = (int)l0 | ((int)l1 << 16); \
    }                                                                           \
    if ((T) + 2 < T_) {  /* issue load x(T+2); used next step */                \
        PG0 = xsrc[(size_t)((T)+2) * (N_*C_)];                                  \
        PG1 = xsrc[(size_t)((T)+2) * (N_*C_) + 1];                              \
    }                                                                           \
    floatx4 accR  = {br, br, br, br};      /* input(3) + kb0(3): depth 6 */     \
    floatx4 accRb = {0.f, 0.f, 0.f, 0.f};  /* kb1(3) */                         \
    floatx4 accZ  = {bz, bz, bz, bz};                                           \
    floatx4 accZb = {0.f, 0.f, 0.f, 0.f};                                       \
    floatx4 accIN = {bin, bin, bin, bin};  /* input only: depth 3 */            \
    floatx4 accHN = {bhn, bhn, bhn, bhn};  /* kb0: depth 3 */                   \
    floatx4 accHNb= {0.f, 0.f, 0.f, 0.f};  /* kb1: depth 3 */                   \
    accR  = MFMA16(ax_hi, wih_hi[0], accR);                                     \
    accR  = MFMA16(ax_hi, wih_lo[0], accR);                                     \
    accR  = MFMA16(ax_lo, wih_hi[0], accR);                                     \
    accZ  = MFMA16(ax_hi, wih_hi[1], accZ);                                     \
    accZ  = MFMA16(ax_hi, wih_lo[1], accZ);                                     \
    accZ  = MFMA16(ax_lo, wih_hi[1], accZ);                                     \
    accIN = MFMA16(ax_hi, wih_hi[2], accIN);                                    \
    accIN = MFMA16(ax_hi, wih_lo[2], accIN);                                    \
    accIN = MFMA16(ax_lo, wih_hi[2], accIN);                                    \
    accR  = MFMA16(ah_hi[0], whh_hi[0][0], accR);                               \
    accR  = MFMA16(ah_hi[0], whh_lo[0][0], accR);                               \
    accR  = MFMA16(ah_lo[0], whh_hi[0][0], accR);                               \
    accZ  = MFMA16(ah_hi[0], whh_hi[1][0], accZ);                               \
    accZ  = MFMA16(ah_hi[0], whh_lo[1][0], accZ);                               \
    accZ  = MFMA16(ah_lo[0], whh_hi[1][0], accZ);                               \
    accHN = MFMA16(ah_hi[0], whh_hi[2][0], accHN);                              \
    accHN = MFMA16(ah_hi[0], whh_lo[2][0], accHN);                              \
    accHN = MFMA16(ah_lo[0], whh_hi[2][0], accHN);                              \
    accRb = MFMA16(ah_hi[1], whh_hi[0][1], accRb);                              \
    accRb = MFMA16(ah_hi[1], whh_lo[0][1], accRb);                              \
    accRb = MFMA16(ah_lo[1], whh_hi[0][1], accRb);                              \
    accZb = MFMA16(ah_hi[1], whh_hi[1][1], accZb);                              \
    accZb = MFMA16(ah_hi[1], whh_lo[1][1], accZb);                              \
    accZb = MFMA16(ah_lo[1], whh_hi[1][1], accZb);                              \
    accHNb= MFMA16(ah_hi[1], whh_hi[2][1], accHNb);                             \
    accHNb= MFMA16(ah_hi[1], whh_lo[2][1], accHNb);                             \
    accHNb= MFMA16(ah_lo[1], whh_hi[2][1], accHNb);                             \
    short* nhh = smem + nxt_*HB_SZ;                                             \
    short* nhl = smem + 2*HB_SZ + nxt_*HB_SZ;                                   \
    _Pragma("unroll")                                                           \
    for (int s = 0; s < 4; ++s) {                                               \
        const float r  = fsig(accR[s] + accRb[s]);                              \
        const float z  = fsig(accZ[s] + accZb[s]);                              \
        const float nn = ftanh(accIN[s] + r * (accHN[s] + accHNb[s]));          \
        const float h  = (1.f - z) * nn + z * hprev[s];                         \
        hprev[s] = h;                                                           \
        const int smp = kgrp*4 + s;                                             \
        unsigned short hh, hl; split2(h, hh, hl);                               \
        const int idx = smp*64 + (jcol ^ ((smp & 7) << 3));                     \
        nhh[idx] = (short)hh;                                                   \
        nhl[idx] = (short)hl;                                                   \
    }                                                                           \
    BARRIER();                                                                  \
} while (0)

    for (int t = 0; t < T_; t += 2) {
        GRU_STEP(t,     0, pA0, pA1, pB0, pB1);
        GRU_STEP(t + 1, 1, pB0, pB1, pA0, pA1);
    }
#undef GRU_STEP

    // ---- write final hidden state (fp32 exact from registers) ----
    #pragma unroll
    for (int s = 0; s < 4; ++s) {
        const int smp = kgrp*4 + s;
        h_last[(size_t)(m0 + smp)*H_ + jcol] = hprev[s];
    }
}

// key/query projections: one wave per sample
__global__ __launch_bounds__(256) void kq_kernel(
    const float* __restrict__ h, const float* __restrict__ wk,
    const float* __restrict__ wq, float* __restrict__ key, float* __restrict__ query)
{
    int wave = (blockIdx.x * 256 + threadIdx.x) >> 6;
    int lane = threadIdx.x & 63;
    float hv = h[(size_t)wave * 64 + lane];
    float kv = hv * wk[lane];
    float qv = hv * wq[lane];
    #pragma unroll
    for (int off = 32; off; off >>= 1) {
        kv += __shfl_down(kv, off);
        qv += __shfl_down(qv, off);
    }
    if (lane == 0) { key[wave] = kv; query[wave] = qv; }
}

__global__ __launch_bounds__(256) void qmax_kernel(const float* __restrict__ query,
                                                   float* __restrict__ qmax)
{
    int b = blockIdx.x, tid = threadIdx.x;
    float m = -INFINITY;
    for (int i = tid; i < N_; i += 256) m = fmaxf(m, query[b*N_ + i]);
    #pragma unroll
    for (int off = 32; off; off >>= 1) m = fmaxf(m, __shfl_down(m, off));
    __shared__ float sm[4];
    if ((tid & 63) == 0) sm[tid >> 6] = m;
    __syncthreads();
    if (tid == 0) qmax[b] = fmaxf(fmaxf(sm[0], sm[1]), fmaxf(sm[2], sm[3]));
}

// softmax denominators: one wave per (b, row). Stores RECIPROCAL of the sum.
__global__ __launch_bounds__(256) void den_kernel(
    const float* __restrict__ key, const float* __restrict__ query,
    const float* __restrict__ qmax, float* __restrict__ den)
{
    int idx  = (blockIdx.x * 256 + threadIdx.x) >> 6;   // b*2048 + i
    int lane = threadIdx.x & 63;
    int b    = idx >> 11;
    float ki = key[idx];
    float mrow = lrelu(ki + qmax[b]);
    const float* q = query + ((size_t)b << 11);
    float sum = 0.f;
    for (int jj = lane; jj < N_; jj += 64)
        sum += __expf(lrelu(ki + q[jj]) - mrow);
    #pragma unroll
    for (int off = 32; off; off >>= 1) sum += __shfl_down(sum, off);
    if (lane == 0) den[idx] = 1.f / sum;    // reciprocal (sum >= 1 always)
}

// adj[i][j] = 0.125 * sum_b (attn[b][i][j] + attn[b][j][i]);  den holds 1/sum
__global__ __launch_bounds__(256) void out_kernel(
    const float* __restrict__ key, const float* __restrict__ query,
    const float* __restrict__ qmax, const float* __restrict__ den,
    float* __restrict__ out)
{
    int flat = blockIdx.x * 256 + threadIdx.x;
    int i = flat >> 11, j = flat & 2047;
    float acc = 0.f;
    #pragma unroll
    for (int b = 0; b < B_; ++b) {
        int bi = (b << 11) + i, bj = (b << 11) + j;
        float ki = key[bi], kj = key[bj];
        float qi = query[bi], qj = query[bj];
        float qm = qmax[b];
        float mi = lrelu(ki + qm), mj = lrelu(kj + qm);
        float aij = __expf(lrelu(ki + qj) - mi) * den[bi];
        float aji = __expf(lrelu(kj + qi) - mj) * den[bj];
        acc += aij + aji;
    }
    out[flat] = 0.125f * acc;
}

extern "C" void kernel_launch(void* const* d_in, const int* in_sizes, int n_in,
                              void* d_out, int out_size, void* d_ws, size_t ws_size,
                              hipStream_t stream) {
    const float* x    = (const float*)d_in[0];
    const float* w_ih = (const float*)d_in[1];
    const float* w_hh = (const float*)d_in[2];
    const float* b_ih = (const float*)d_in[3];
    const float* b_hh = (const float*)d_in[4];
    const float* wk   = (const float*)d_in[5];
    const float* wq   = (const float*)d_in[6];
    float* out = (float*)d_out;
    float* ws  = (float*)d_ws;

    // Bulk scratch (h_last, 2 MB) lives in d_out: dead before out_kernel
    // (the final launch) overwrites the entire 16 MB output.
    float* h_last = out;                      // [0, 524288) floats of d_out
    float* key    = ws;                       // 8192
    float* query  = ws + 8192;                // 8192
    float* qmax   = ws + 16384;               // 4
    float* den    = ws + 16388;               // 8192

    gru_kernel<<<M_/SPB, 256, 0, stream>>>(x, w_ih, w_hh, b_ih, b_hh, h_last);
    kq_kernel<<<M_/4, 256, 0, stream>>>(h_last, wk, wq, key, query);
    qmax_kernel<<<B_, 256, 0, stream>>>(query, qmax);
    den_kernel<<<M_/4, 256, 0, stream>>>(key, query, qmax, den);
    out_kernel<<<(N_*N_)/256, 256, 0, stream>>>(key, query, qmax, den, out);
}

// Round 6
// 133.011 us; speedup vs baseline: 5.1425x; 1.0025x over previous
//
#include <hip/hip_runtime.h>
#include <math.h>

#define B_ 4
#define T_ 64
#define N_ 2048
#define C_ 32
#define H_ 64
#define M_ (B_*N_)      // 8192
#define SPB 16          // samples per GRU block (one 16-row M-tile)
#define SLOPE 0.2f

typedef __attribute__((ext_vector_type(8))) short short8;   // 8 bf16 (4 VGPRs)
typedef __attribute__((ext_vector_type(4))) float floatx4;  // MFMA acc

#define MFMA16(a,b,c) __builtin_amdgcn_mfma_f32_16x16x32_bf16(a,b,c,0,0,0)

// Barrier that does NOT drain vmcnt: LDS visibility via lgkmcnt(0), global
// prefetch loads stay in flight across the barrier.
#define BARRIER() asm volatile("s_waitcnt lgkmcnt(0)\n\ts_barrier" ::: "memory")

__device__ __forceinline__ float lrelu(float v) { return v >= 0.f ? v : SLOPE * v; }
__device__ __forceinline__ float fsig(float x)  { return 1.f / (1.f + __expf(-x)); }
__device__ __forceinline__ float ftanh(float x) { return 1.f - 2.f / (__expf(2.f * x) + 1.f); }

__device__ __forceinline__ unsigned short bf16_rtn(float f) {
    unsigned u = __float_as_uint(f);
    return (unsigned short)((u + 0x7fffu + ((u >> 16) & 1u)) >> 16);
}
__device__ __forceinline__ float bf16_f32(unsigned short s) {
    return __uint_as_float(((unsigned)s) << 16);
}
__device__ __forceinline__ void split2(float f, unsigned short& h, unsigned short& l) {
    h = bf16_rtn(f);
    l = bf16_rtn(f - bf16_f32(h));
}

// LDS (shorts): [hb_hi b0 | hb_hi b1 | hb_lo b0 | hb_lo b1 | xb_hi b0 | xb_hi b1 | xb_lo b0 | xb_lo b1]
#define HB_SZ (16*64)   // 1024 shorts = 2 KB per component per buffer
#define XB_SZ (64*8)    //  512 shorts = 1 KB per component per buffer

// waves_per_eu(2,2): the 512-block grid supplies exactly 2 blocks/CU = 2
// waves/SIMD. Pin the allocator to that occupancy so the ~160-VGPR working
// set (72 weight + 28 acc + 24 frag + misc) is allocated cleanly instead of
// being squeezed into 96 VGPRs with AGPR-shuffle/remat traffic (round-5
// counters: VALUBusy implied ~3x the source-level VALU op count).
__global__ __attribute__((amdgpu_flat_work_group_size(256, 256),
                          amdgpu_waves_per_eu(2, 2)))
void gru_kernel(
    const float* __restrict__ x,      // [B,T,N,C]
    const float* __restrict__ w_ih,   // [192][32]
    const float* __restrict__ w_hh,   // [192][64]
    const float* __restrict__ b_ih,   // [192]
    const float* __restrict__ b_hh,   // [192]
    float* __restrict__ h_last)       // [M][H]  (d_out scratch)
{
    __shared__ short smem[4*HB_SZ + 4*XB_SZ];

    const int tid   = threadIdx.x;
    const int lane  = tid & 63;
    const int w     = tid >> 6;        // wave 0..3 -> owns N-tiles {w, w+4, w+8}
    const int col16 = lane & 15;
    const int kgrp  = lane >> 4;       // 0..3

    const int m0 = blockIdx.x * SPB;
    const int b  = m0 >> 11;
    const int n0 = m0 & 2047;

    // ---- weight B-fragments -> registers (once). B[k][col] = w[col][k]. ----
    short8 whh_hi[3][2], whh_lo[3][2], wih_hi[3], wih_lo[3];
    #pragma unroll
    for (int g = 0; g < 3; ++g) {
        const int colj = g*64 + w*16 + col16;
        #pragma unroll
        for (int kb = 0; kb < 2; ++kb) {
            const float* src = w_hh + colj*64 + kb*32 + kgrp*8;
            short8 hi, lo;
            #pragma unroll
            for (int e = 0; e < 8; ++e) {
                unsigned short h_, l_; split2(src[e], h_, l_);
                hi[e] = (short)h_; lo[e] = (short)l_;
            }
            whh_hi[g][kb] = hi; whh_lo[g][kb] = lo;
        }
        {
            const float* src = w_ih + colj*32 + kgrp*8;
            short8 hi, lo;
            #pragma unroll
            for (int e = 0; e < 8; ++e) {
                unsigned short h_, l_; split2(src[e], h_, l_);
                hi[e] = (short)h_; lo[e] = (short)l_;
            }
            wih_hi[g] = hi; wih_lo[g] = lo;
        }
    }

    const int jcol = w*16 + col16;
    const float br  = b_ih[jcol]       + b_hh[jcol];
    const float bz  = b_ih[64 + jcol]  + b_hh[64 + jcol];
    const float bin = b_ih[128 + jcol];
    const float bhn = b_hh[128 + jcol];

    // per-thread x staging geometry (2 floats/thread/step)
    const int fl  = tid >> 2;                 // frag-lane 0..63
    const int row = fl & 15;
    const int kk  = (fl >> 4) * 8 + (tid & 3) * 2;
    const int xii = fl*4 + (tid & 3);
    const float* xsrc = x + (((size_t)b * T_) * N_ + (n0 + row)) * C_ + kk;

    // ---- prologue: zero h buf0; stage x(0) into buf0; issue x(1) prefetch ----
    for (int i = tid; i < HB_SZ; i += 256) { smem[i] = 0; smem[2*HB_SZ + i] = 0; }
    {
        unsigned short h0,l0,h1,l1;
        split2(xsrc[0], h0, l0); split2(xsrc[1], h1, l1);
        ((int*)(smem + 4*HB_SZ))[xii]            = (int)h0 | ((int)h1 << 16);
        ((int*)(smem + 4*HB_SZ + 2*XB_SZ))[xii]  = (int)l0 | ((int)l1 << 16);
    }
    float pA0 = xsrc[N_*C_], pA1 = xsrc[N_*C_ + 1];   // x(1)
    float pB0 = 0.f, pB1 = 0.f;
    BARRIER();

    float hprev[4] = {0.f, 0.f, 0.f, 0.f};

#define GRU_STEP(T, CUR, PF0, PF1, PG0, PG1) do {                               \
    const int nxt_ = (CUR) ^ 1;                                                 \
    const short* hbh = smem + (CUR)*HB_SZ;                                      \
    const short* hbl = smem + 2*HB_SZ + (CUR)*HB_SZ;                            \
    const short* xbh = smem + 4*HB_SZ + (CUR)*XB_SZ;                            \
    const short* xbl = smem + 4*HB_SZ + 2*XB_SZ + (CUR)*XB_SZ;                  \
    short8 ah_hi[2], ah_lo[2];                                                  \
    _Pragma("unroll")                                                           \
    for (int kb = 0; kb < 2; ++kb) {                                            \
        const int kidx = kgrp*8 + kb*32;                                        \
        const int idx  = col16*64 + (kidx ^ ((col16 & 7) << 3));                \
        ah_hi[kb] = *(const short8*)(hbh + idx);                                \
        ah_lo[kb] = *(const short8*)(hbl + idx);                                \
    }                                                                           \
    const short8 ax_hi = *(const short8*)(xbh + lane*8);                        \
    const short8 ax_lo = *(const short8*)(xbl + lane*8);                        \
    if ((T) + 1 < T_) {  /* store x(T+1) from regs loaded one step ago */       \
        unsigned short h0,l0,h1,l1;                                             \
        split2(PF0, h0, l0); split2(PF1, h1, l1);                               \
        ((int*)(smem + 4*HB_SZ + nxt_*XB_SZ))[xii]           = (int)h0 | ((int)h1 << 16); \
        ((int*)(smem + 4*HB_SZ + 2*XB_SZ + nxt_*XB_SZ))[xii] = (int)l0 | ((int)l1 << 16); \
    }                                                                           \
    if ((T) + 2 < T_) {  /* issue load x(T+2); used next step */                \
        PG0 = xsrc[(size_t)((T)+2) * (N_*C_)];                                  \
        PG1 = xsrc[(size_t)((T)+2) * (N_*C_) + 1];                              \
    }                                                                           \
    floatx4 accR  = {br, br, br, br};                                           \
    floatx4 accRb = {0.f, 0.f, 0.f, 0.f};                                       \
    floatx4 accZ  = {bz, bz, bz, bz};                                           \
    floatx4 accZb = {0.f, 0.f, 0.f, 0.f};                                       \
    floatx4 accIN = {bin, bin, bin, bin};                                       \
    floatx4 accHN = {bhn, bhn, bhn, bhn};                                       \
    floatx4 accHNb= {0.f, 0.f, 0.f, 0.f};                                       \
    accR  = MFMA16(ax_hi, wih_hi[0], accR);                                     \
    accR  = MFMA16(ax_hi, wih_lo[0], accR);                                     \
    accR  = MFMA16(ax_lo, wih_hi[0], accR);                                     \
    accZ  = MFMA16(ax_hi, wih_hi[1], accZ);                                     \
    accZ  = MFMA16(ax_hi, wih_lo[1], accZ);                                     \
    accZ  = MFMA16(ax_lo, wih_hi[1], accZ);                                     \
    accIN = MFMA16(ax_hi, wih_hi[2], accIN);                                    \
    accIN = MFMA16(ax_hi, wih_lo[2], accIN);                                    \
    accIN = MFMA16(ax_lo, wih_hi[2], accIN);                                    \
    accR  = MFMA16(ah_hi[0], whh_hi[0][0], accR);                               \
    accR  = MFMA16(ah_hi[0], whh_lo[0][0], accR);                               \
    accR  = MFMA16(ah_lo[0], whh_hi[0][0], accR);                               \
    accZ  = MFMA16(ah_hi[0], whh_hi[1][0], accZ);                               \
    accZ  = MFMA16(ah_hi[0], whh_lo[1][0], accZ);                               \
    accZ  = MFMA16(ah_lo[0], whh_hi[1][0], accZ);                               \
    accHN = MFMA16(ah_hi[0], whh_hi[2][0], accHN);                              \
    accHN = MFMA16(ah_hi[0], whh_lo[2][0], accHN);                              \
    accHN = MFMA16(ah_lo[0], whh_hi[2][0], accHN);                              \
    accRb = MFMA16(ah_hi[1], whh_hi[0][1], accRb);                              \
    accRb = MFMA16(ah_hi[1], whh_lo[0][1], accRb);                              \
    accRb = MFMA16(ah_lo[1], whh_hi[0][1], accRb);                              \
    accZb = MFMA16(ah_hi[1], whh_hi[1][1], accZb);                              \
    accZb = MFMA16(ah_hi[1], whh_lo[1][1], accZb);                              \
    accZb = MFMA16(ah_lo[1], whh_hi[1][1], accZb);                              \
    accHNb= MFMA16(ah_hi[1], whh_hi[2][1], accHNb);                             \
    accHNb= MFMA16(ah_hi[1], whh_lo[2][1], accHNb);                             \
    accHNb= MFMA16(ah_lo[1], whh_hi[2][1], accHNb);                             \
    short* nhh = smem + nxt_*HB_SZ;                                             \
    short* nhl = smem + 2*HB_SZ + nxt_*HB_SZ;                                   \
    _Pragma("unroll")                                                           \
    for (int s = 0; s < 4; ++s) {                                               \
        const float r  = fsig(accR[s] + accRb[s]);                              \
        const float z  = fsig(accZ[s] + accZb[s]);                              \
        const float nn = ftanh(accIN[s] + r * (accHN[s] + accHNb[s]));          \
        const float h  = (1.f - z) * nn + z * hprev[s];                         \
        hprev[s] = h;                                                           \
        const int smp = kgrp*4 + s;                                             \
        unsigned short hh, hl; split2(h, hh, hl);                               \
        const int idx = smp*64 + (jcol ^ ((smp & 7) << 3));                     \
        nhh[idx] = (short)hh;                                                   \
        nhl[idx] = (short)hl;                                                   \
    }                                                                           \
    BARRIER();                                                                  \
} while (0)

    for (int t = 0; t < T_; t += 2) {
        GRU_STEP(t,     0, pA0, pA1, pB0, pB1);
        GRU_STEP(t + 1, 1, pB0, pB1, pA0, pA1);
    }
#undef GRU_STEP

    // ---- write final hidden state (fp32 exact from registers) ----
    #pragma unroll
    for (int s = 0; s < 4; ++s) {
        const int smp = kgrp*4 + s;
        h_last[(size_t)(m0 + smp)*H_ + jcol] = hprev[s];
    }
}

// key/query projections: one wave per sample
__global__ __launch_bounds__(256) void kq_kernel(
    const float* __restrict__ h, const float* __restrict__ wk,
    const float* __restrict__ wq, float* __restrict__ key, float* __restrict__ query)
{
    int wave = (blockIdx.x * 256 + threadIdx.x) >> 6;
    int lane = threadIdx.x & 63;
    float hv = h[(size_t)wave * 64 + lane];
    float kv = hv * wk[lane];
    float qv = hv * wq[lane];
    #pragma unroll
    for (int off = 32; off; off >>= 1) {
        kv += __shfl_down(kv, off);
        qv += __shfl_down(qv, off);
    }
    if (lane == 0) { key[wave] = kv; query[wave] = qv; }
}

__global__ __launch_bounds__(256) void qmax_kernel(const float* __restrict__ query,
                                                   float* __restrict__ qmax)
{
    int b = blockIdx.x, tid = threadIdx.x;
    float m = -INFINITY;
    for (int i = tid; i < N_; i += 256) m = fmaxf(m, query[b*N_ + i]);
    #pragma unroll
    for (int off = 32; off; off >>= 1) m = fmaxf(m, __shfl_down(m, off));
    __shared__ float sm[4];
    if ((tid & 63) == 0) sm[tid >> 6] = m;
    __syncthreads();
    if (tid == 0) qmax[b] = fmaxf(fmaxf(sm[0], sm[1]), fmaxf(sm[2], sm[3]));
}

// softmax denominators: one wave per (b, row). Stores RECIPROCAL of the sum.
__global__ __launch_bounds__(256) void den_kernel(
    const float* __restrict__ key, const float* __restrict__ query,
    const float* __restrict__ qmax, float* __restrict__ den)
{
    int idx  = (blockIdx.x * 256 + threadIdx.x) >> 6;   // b*2048 + i
    int lane = threadIdx.x & 63;
    int b    = idx >> 11;
    float ki = key[idx];
    float mrow = lrelu(ki + qmax[b]);
    const float* q = query + ((size_t)b << 11);
    float sum = 0.f;
    for (int jj = lane; jj < N_; jj += 64)
        sum += __expf(lrelu(ki + q[jj]) - mrow);
    #pragma unroll
    for (int off = 32; off; off >>= 1) sum += __shfl_down(sum, off);
    if (lane == 0) den[idx] = 1.f / sum;    // reciprocal (sum >= 1 always)
}

// adj[i][j] = 0.125 * sum_b (attn[b][i][j] + attn[b][j][i]);  den holds 1/sum
__global__ __launch_bounds__(256) void out_kernel(
    const float* __restrict__ key, const float* __restrict__ query,
    const float* __restrict__ qmax, const float* __restrict__ den,
    float* __restrict__ out)
{
    int flat = blockIdx.x * 256 + threadIdx.x;
    int i = flat >> 11, j = flat & 2047;
    float acc = 0.f;
    #pragma unroll
    for (int b = 0; b < B_; ++b) {
        int bi = (b << 11) + i, bj = (b << 11) + j;
        float ki = key[bi], kj = key[bj];
        float qi = query[bi], qj = query[bj];
        float qm = qmax[b];
        float mi = lrelu(ki + qm), mj = lrelu(kj + qm);
        float aij = __expf(lrelu(ki + qj) - mi) * den[bi];
        float aji = __expf(lrelu(kj + qi) - mj) * den[bj];
        acc += aij + aji;
    }
    out[flat] = 0.125f * acc;
}

extern "C" void kernel_launch(void* const* d_in, const int* in_sizes, int n_in,
                              void* d_out, int out_size, void* d_ws, size_t ws_size,
                              hipStream_t stream) {
    const float* x    = (const float*)d_in[0];
    const float* w_ih = (const float*)d_in[1];
    const float* w_hh = (const float*)d_in[2];
    const float* b_ih = (const float*)d_in[3];
    const float* b_hh = (const float*)d_in[4];
    const float* wk   = (const float*)d_in[5];
    const float* wq   = (const float*)d_in[6];
    float* out = (float*)d_out;
    float* ws  = (float*)d_ws;

    // Bulk scratch (h_last, 2 MB) lives in d_out: dead before out_kernel
    // (the final launch) overwrites the entire 16 MB output.
    float* h_last = out;                      // [0, 524288) floats of d_out
    float* key    = ws;                       // 8192
    float* query  = ws + 8192;                // 8192
    float* qmax   = ws + 16384;               // 4
    float* den    = ws + 16388;               // 8192

    gru_kernel<<<M_/SPB, 256, 0, stream>>>(x, w_ih, w_hh, b_ih, b_hh, h_last);
    kq_kernel<<<M_/4, 256, 0, stream>>>(h_last, wk, wq, key, query);
    qmax_kernel<<<B_, 256, 0, stream>>>(query, qmax);
    den_kernel<<<M_/4, 256, 0, stream>>>(key, query, qmax, den);
    out_kernel<<<(N_*N_)/256, 256, 0, stream>>>(key, query, qmax, den, out);
}